// Round 7
// baseline (96.874 us; speedup 1.0000x reference)
//
#include <hip/hip_runtime.h>
#include <math.h>

#define NN 4
#define LL 4096
#define HH 8
#define EE 64
#define CHK 64            // compute chunk rows
#define GSUP 4            // chunks per super-chunk
#define SUPC (CHK*GSUP)   // 256 rows
#define NSUP (LL/SUPC)    // 16 supers per (n,h)
#define NH (NN*HH)        // 32
#define NBLK (NH*NSUP)    // 512 blocks
#define NCH64 (LL/CHK)    // 64 chunks per (n,h)
#define EPSF 1e-6f

typedef float f32x4 __attribute__((ext_vector_type(4)));
typedef __bf16 bf16x8 __attribute__((ext_vector_type(8)));

__device__ __forceinline__ float phi_map(float x) {
  return x > 0.0f ? x + 1.0f : __expf(x);
}

#define MFMA(a, b, c) __builtin_amdgcn_mfma_f32_16x16x32_bf16((a), (b), (c), 0, 0, 0)

// ---- swizzled [64 rows][64 d] bf16 tile: 16B-block XOR along d (proven 0-conflict) ----
__device__ __forceinline__ int swz64(int row, int d) {
  return row * 64 + (d & 7) + 8 * ((d >> 3) ^ ((row >> 2) & 7));
}
__device__ __forceinline__ int frag64(int row, int blk) {
  return row * 64 + 8 * (blk ^ ((row >> 2) & 7));
}

// ================= Kernel 1: per-super-chunk S^T = sum_4tiles V^T K; per-64-chunk ksum =================
#define K1_ISSUE(J, BUF) { \
  const int l0i = (sc * GSUP + (J)) * CHK; \
  _Pragma("unroll") for (int it = 0; it < 4; ++it) { \
    int f = t + 256 * it; int d = f >> 4; int c4 = (f & 15) << 2; \
    size_t gb = (((size_t)n * LL + (size_t)(l0i + d)) * HH + h) * EE + c4; \
    pk[BUF][it] = *(const float4*)(Kg + gb); \
    pv[BUF][it] = *(const float4*)(Vg + gb); \
    pl[BUF][it] = KLg[n * LL + l0i + d]; } }

#define K1_STAGE(BUF) { \
  _Pragma("unroll") for (int it = 0; it < 4; ++it) { \
    int f = t + 256 * it; int d = f >> 4; int c4 = (f & 15) << 2; \
    float klr = pl[BUF][it]; float4 kk = pk[BUF][it]; float4 vv = pv[BUF][it]; \
    float ka[4] = {phi_map(kk.x) * klr, phi_map(kk.y) * klr, phi_map(kk.z) * klr, phi_map(kk.w) * klr}; \
    float va[4] = {vv.x, vv.y, vv.z, vv.w}; \
    _Pragma("unroll") for (int jj = 0; jj < 4; ++jj) { \
      sKt[BUF][swz64(c4 + jj, d)] = (__bf16)ka[jj]; \
      sVt[BUF][swz64(c4 + jj, d)] = (__bf16)va[jj]; } } }

__global__ __launch_bounds__(256, 2) void k_chunksums(
    const float* __restrict__ Kg, const float* __restrict__ Vg,
    const float* __restrict__ KLg, __bf16* __restrict__ ScG, __bf16* __restrict__ KscG)
{
  __shared__ __bf16 sKt[2][4096];
  __shared__ __bf16 sVt[2][4096];
  const int g = blockIdx.x;        // nh*NSUP + sc
  const int sc = g % NSUP;
  const int nh = g / NSUP;
  const int h = nh % HH;
  const int n = nh / HH;
  const int t = threadIdx.x;
  const int w = t >> 6;
  const int lane = t & 63;
  const int lg = lane >> 4;
  const int li = lane & 15;

  float4 pk[2][4], pv[2][4];
  float pl[2][4];

  K1_ISSUE(0, 0);
  K1_STAGE(0);

  f32x4 acc[4];
  #pragma unroll
  for (int nt = 0; nt < 4; ++nt) acc[nt] = (f32x4){0.f, 0.f, 0.f, 0.f};

  bf16x8 ones;
  #pragma unroll
  for (int i = 0; i < 8; ++i) ones[i] = (__bf16)1.0f;

  #pragma unroll
  for (int j = 0; j < GSUP; ++j) {
    if (j + 1 < GSUP) K1_ISSUE(j + 1, (j + 1) & 1);
    __syncthreads();

    bf16x8 aV0 = *(const bf16x8*)&sVt[j & 1][frag64(16 * w + li, lg)];
    bf16x8 aV1 = *(const bf16x8*)&sVt[j & 1][frag64(16 * w + li, 4 + lg)];

    f32x4 accK[4];
    #pragma unroll
    for (int nt = 0; nt < 4; ++nt) accK[nt] = (f32x4){0.f, 0.f, 0.f, 0.f};

    #pragma unroll
    for (int nt = 0; nt < 4; ++nt) {
      bf16x8 b0 = *(const bf16x8*)&sKt[j & 1][frag64(li + 16 * nt, lg)];
      bf16x8 b1 = *(const bf16x8*)&sKt[j & 1][frag64(li + 16 * nt, 4 + lg)];
      acc[nt] = MFMA(aV0, b0, acc[nt]);
      acc[nt] = MFMA(aV1, b1, acc[nt]);
      if (w == 0) {
        accK[nt] = MFMA(ones, b0, accK[nt]);
        accK[nt] = MFMA(ones, b1, accK[nt]);
      }
    }
    if (w == 0 && lg == 0) {
      #pragma unroll
      for (int nt = 0; nt < 4; ++nt)
        KscG[(size_t)(g * GSUP + j) * 64 + li + 16 * nt] = (__bf16)accK[nt][0];
    }
    if (j + 1 < GSUP) K1_STAGE((j + 1) & 1);
  }

  __bf16* sp = ScG + (size_t)g * 4096;
  #pragma unroll
  for (int nt = 0; nt < 4; ++nt)
    #pragma unroll
    for (int reg = 0; reg < 4; ++reg)
      sp[(16 * w + 4 * lg + reg) * 64 + li + 16 * nt] = (__bf16)acc[nt][reg];
}

// ================= Kernel 2: exclusive prefixes =================
__global__ __launch_bounds__(256) void k_prefix(
    __bf16* __restrict__ Sc, __bf16* __restrict__ Ksc)
{
  const int bid = blockIdx.x;
  const int t = threadIdx.x;
  if (bid < NH * 16) {
    const int nh = bid >> 4;
    const int strip = bid & 15;
    const int entry = strip * 256 + t;
    __bf16 v[NSUP];
    #pragma unroll
    for (int c = 0; c < NSUP; ++c)
      v[c] = Sc[((size_t)(nh * NSUP + c) << 12) + entry];
    float run = 0.0f;
    #pragma unroll
    for (int c = 0; c < NSUP; ++c) {
      Sc[((size_t)(nh * NSUP + c) << 12) + entry] = (__bf16)run;
      run += (float)v[c];
    }
  } else {
    const int idx = (bid - NH * 16) * 256 + t;
    const int nh = idx >> 6;
    const int e = idx & 63;
    __bf16 v[NCH64];
    #pragma unroll
    for (int c = 0; c < NCH64; ++c)
      v[c] = Ksc[((size_t)(nh * NCH64 + c) << 6) + e];
    float run = 0.0f;
    #pragma unroll
    for (int c = 0; c < NCH64; ++c) {
      Ksc[((size_t)(nh * NCH64 + c) << 6) + e] = (__bf16)run;
      run += (float)v[c];
    }
  }
}

// ================= Kernel 3: 4-wave per-super-chunk output, single-buffered LDS =================
#define P2_ISSUE(CC) { \
  const int l0i = (sc * GSUP + (CC)) * CHK; \
  _Pragma("unroll") for (int it = 0; it < 4; ++it) { \
    int f = t + 256 * it; int d = f >> 4; int c4 = (f & 15) << 2; \
    size_t gb = (((size_t)n * LL + (size_t)(l0i + d)) * HH + h) * EE + c4; \
    pk[it] = *(const float4*)(Kg + gb); \
    pv[it] = *(const float4*)(Vg + gb); \
    pl[it] = KLg[n * LL + l0i + d]; } \
  { const float* qr = Qg + (((size_t)n * LL + (size_t)(l0i + arow)) * HH + h) * EE; \
    pq[0] = *(const float4*)(qr + 8 * lg); \
    pq[1] = *(const float4*)(qr + 8 * lg + 4); \
    pq[2] = *(const float4*)(qr + 32 + 8 * lg); \
    pq[3] = *(const float4*)(qr + 32 + 8 * lg + 4); } }

#define P2_STAGE(QB) { \
  _Pragma("unroll") for (int it = 0; it < 4; ++it) { \
    int f = t + 256 * it; int d = f >> 4; int c4 = (f & 15) << 2; \
    float klr = pl[it]; float4 kk = pk[it]; float4 vv = pv[it]; \
    float ka[4] = {phi_map(kk.x) * klr, phi_map(kk.y) * klr, phi_map(kk.z) * klr, phi_map(kk.w) * klr}; \
    float va[4] = {vv.x, vv.y, vv.z, vv.w}; \
    __bf16* kd = &sK[d][c4]; \
    kd[0] = (__bf16)ka[0]; kd[1] = (__bf16)ka[1]; kd[2] = (__bf16)ka[2]; kd[3] = (__bf16)ka[3]; \
    _Pragma("unroll") for (int jj = 0; jj < 4; ++jj) { \
      sKt[swz64(c4 + jj, d)] = (__bf16)ka[jj]; \
      sVt[swz64(c4 + jj, d)] = (__bf16)va[jj]; } } \
  { float4 q0 = pq[0], q1 = pq[1], q2 = pq[2], q3 = pq[3]; \
    bf16x8 a0, a1; \
    a0[0] = (__bf16)phi_map(q0.x); a0[1] = (__bf16)phi_map(q0.y); \
    a0[2] = (__bf16)phi_map(q0.z); a0[3] = (__bf16)phi_map(q0.w); \
    a0[4] = (__bf16)phi_map(q1.x); a0[5] = (__bf16)phi_map(q1.y); \
    a0[6] = (__bf16)phi_map(q1.z); a0[7] = (__bf16)phi_map(q1.w); \
    a1[0] = (__bf16)phi_map(q2.x); a1[1] = (__bf16)phi_map(q2.y); \
    a1[2] = (__bf16)phi_map(q2.z); a1[3] = (__bf16)phi_map(q2.w); \
    a1[4] = (__bf16)phi_map(q3.x); a1[5] = (__bf16)phi_map(q3.y); \
    a1[6] = (__bf16)phi_map(q3.z); a1[7] = (__bf16)phi_map(q3.w); \
    aQ[QB][0] = a0; aQ[QB][1] = a1; } }

__global__ __launch_bounds__(256, 4) void k_pass2(
    const float* __restrict__ Qg, const float* __restrict__ Kg,
    const float* __restrict__ Vg, const float* __restrict__ KLg,
    const __bf16* __restrict__ Sp, const __bf16* __restrict__ Ksp,
    float* __restrict__ Og)
{
  __shared__ __bf16 sK[64][72];   // phi(K)*kl row-major [d][e]   (attn B)
  __shared__ __bf16 sKt[4096];    // K^T [e][d] swizzled          (state B)
  __shared__ __bf16 sVt[4096];    // V^T [m][d] swizzled          (PV B / state A)
  __shared__ __bf16 sU[4096];     // S^T [m][e] swizzled; P overlay between barriers B..A

  const int g = blockIdx.x;       // nh*NSUP + sc
  const int sc = g % NSUP;
  const int nh = g / NSUP;
  const int h = nh % HH;
  const int n = nh / HH;
  const int t = threadIdx.x;
  const int w = t >> 6;
  const int lane = t & 63;
  const int lg = lane >> 4;
  const int li = lane & 15;
  const int arow = 16 * w + li;

  float4 pk[4], pv[4], pq[4];
  float pl[4];
  bf16x8 aQ[2][2];

  // ---- stage S^T super-prefix into sU (swizzled) ----
  {
    const bf16x8* sp8 = (const bf16x8*)(Sp + (size_t)g * 4096);
    bf16x8 s0 = sp8[2 * t];
    bf16x8 s1 = sp8[2 * t + 1];
    int m = t >> 2, eb = (t & 3) * 2;
    *(bf16x8*)&sU[frag64(m, eb)] = s0;
    *(bf16x8*)&sU[frag64(m, eb + 1)] = s1;
  }

  P2_ISSUE(0);
  P2_STAGE(0);

  f32x4 accS[4];

  #pragma unroll
  for (int cc = 0; cc < GSUP; ++cc) {
    __syncthreads();   // A: STAGE(cc) + sU (initial or state writeback) visible

    if (cc == 0) {
      // seed state accumulator with the super-prefix (C-frag positions)
      #pragma unroll
      for (int nt = 0; nt < 4; ++nt)
        #pragma unroll
        for (int reg = 0; reg < 4; ++reg)
          accS[nt][reg] = (float)sU[swz64(16 * w + 4 * lg + reg, li + 16 * nt)];
    }

    if (cc + 1 < GSUP) P2_ISSUE(cc + 1);   // regs free (STAGE(cc) consumed them)

    bf16x8 aQ0 = aQ[cc & 1][0], aQ1 = aQ[cc & 1][1];

    // ---- inter: acc = Q * S ----
    f32x4 acc[4];
    #pragma unroll
    for (int nt = 0; nt < 4; ++nt) {
      acc[nt] = (f32x4){0.f, 0.f, 0.f, 0.f};
      bf16x8 b0 = *(const bf16x8*)&sU[frag64(li + 16 * nt, lg)];
      bf16x8 b1 = *(const bf16x8*)&sU[frag64(li + 16 * nt, 4 + lg)];
      acc[nt] = MFMA(aQ0, b0, acc[nt]);
      acc[nt] = MFMA(aQ1, b1, acc[nt]);
    }

    // ---- den = q . ksum_prefix ----
    const __bf16* kb = Ksp + (size_t)(g * GSUP + cc) * 64;
    bf16x8 ks0 = *(const bf16x8*)(kb + 8 * lg);
    bf16x8 ks1 = *(const bf16x8*)(kb + 32 + 8 * lg);
    float dv = 0.0f;
    #pragma unroll
    for (int i = 0; i < 8; ++i) {
      dv += (float)aQ0[i] * (float)ks0[i];
      dv += (float)aQ1[i] * (float)ks1[i];
    }
    dv += __shfl_xor(dv, 16);
    dv += __shfl_xor(dv, 32);
    float den[4];
    #pragma unroll
    for (int reg = 0; reg < 4; ++reg) den[reg] = __shfl(dv, 4 * lg + reg);

    __syncthreads();   // B: all sU inter-reads done -> P may overlay

    // ---- intra: masked attn -> P into sU (each wave overlays its own 16 rows) ----
    float rs[4] = {0.f, 0.f, 0.f, 0.f};
    #pragma unroll
    for (int nt = 0; nt < 4; ++nt) {
      f32x4 at2 = (f32x4){0.f, 0.f, 0.f, 0.f};
      if (nt <= w) {
        bf16x8 b0 = *(const bf16x8*)&sK[li + 16 * nt][8 * lg];
        bf16x8 b1 = *(const bf16x8*)&sK[li + 16 * nt][32 + 8 * lg];
        at2 = MFMA(aQ0, b0, at2);
        at2 = MFMA(aQ1, b1, at2);
      }
      #pragma unroll
      for (int reg = 0; reg < 4; ++reg) {
        int row = 16 * w + 4 * lg + reg;
        int col = li + 16 * nt;
        float av = (col <= row) ? at2[reg] : 0.0f;
        rs[reg] += av;
        sU[swz64(row, col)] = (__bf16)av;
      }
    }

    // ---- rowsum reduce (within wave: cols are fully wave-local) ----
    #pragma unroll
    for (int reg = 0; reg < 4; ++reg) {
      float v = rs[reg];
      v += __shfl_xor(v, 1);
      v += __shfl_xor(v, 2);
      v += __shfl_xor(v, 4);
      v += __shfl_xor(v, 8);
      rs[reg] = v;
    }

    // ---- PV: acc += P * V  (P rows are wave-private; no barrier needed) ----
    {
      bf16x8 aP0 = *(const bf16x8*)&sU[frag64(arow, lg)];
      bf16x8 aP1 = aP0;
      if (w >= 2) aP1 = *(const bf16x8*)&sU[frag64(arow, 4 + lg)];
      #pragma unroll
      for (int nt = 0; nt < 4; ++nt) {
        bf16x8 bv0 = *(const bf16x8*)&sVt[frag64(li + 16 * nt, lg)];
        acc[nt] = MFMA(aP0, bv0, acc[nt]);
        if (w >= 2) {
          bf16x8 bv1 = *(const bf16x8*)&sVt[frag64(li + 16 * nt, 4 + lg)];
          acc[nt] = MFMA(aP1, bv1, acc[nt]);
        }
      }
    }

    // ---- normalize + store ----
    const int l0 = (sc * GSUP + cc) * CHK;
    #pragma unroll
    for (int reg = 0; reg < 4; ++reg) {
      float inv = 1.0f / (den[reg] + rs[reg] + EPSF);
      int row = l0 + 16 * w + 4 * lg + reg;
      size_t ob = (((size_t)n * LL + row) * HH + h) * EE + li;
      #pragma unroll
      for (int nt = 0; nt < 4; ++nt)
        Og[ob + 16 * nt] = acc[nt][reg] * inv;
    }

    // ---- state update S^T += K^T V; write back into sU (own rows, clobbers P) ----
    if (cc + 1 < GSUP) {
      bf16x8 aV0 = *(const bf16x8*)&sVt[frag64(arow, lg)];
      bf16x8 aV1 = *(const bf16x8*)&sVt[frag64(arow, 4 + lg)];
      #pragma unroll
      for (int nt = 0; nt < 4; ++nt) {
        bf16x8 bk0 = *(const bf16x8*)&sKt[frag64(li + 16 * nt, lg)];
        bf16x8 bk1 = *(const bf16x8*)&sKt[frag64(li + 16 * nt, 4 + lg)];
        accS[nt] = MFMA(aV0, bk0, accS[nt]);
        accS[nt] = MFMA(aV1, bk1, accS[nt]);
        #pragma unroll
        for (int reg = 0; reg < 4; ++reg)
          sU[swz64(16 * w + 4 * lg + reg, li + 16 * nt)] = (__bf16)accS[nt][reg];
      }

      __syncthreads();   // C: all reads of sK/sKt/sVt for chunk cc done -> restage
      P2_STAGE((cc + 1) & 1);
    }
  }
}

extern "C" void kernel_launch(void* const* d_in, const int* in_sizes, int n_in,
                              void* d_out, int out_size, void* d_ws, size_t ws_size,
                              hipStream_t stream) {
  const float* Qg  = (const float*)d_in[0];
  const float* Kg  = (const float*)d_in[1];
  const float* Vg  = (const float*)d_in[2];
  const float* KLg = (const float*)d_in[3];
  float* Og = (float*)d_out;

  // ws: Sc bf16 512*4096*2 = 4MB | Ksc bf16 2048*64*2 = 256KB (prefix in place)
  __bf16* Sc  = (__bf16*)d_ws;
  __bf16* Ksc = (__bf16*)((char*)d_ws + (size_t)NBLK * 4096 * 2);

  hipLaunchKernelGGL(k_chunksums, dim3(NBLK), dim3(256), 0, stream, Kg, Vg, KLg, Sc, Ksc);
  hipLaunchKernelGGL(k_prefix, dim3(NH * 16 + 8), dim3(256), 0, stream, Sc, Ksc);
  hipLaunchKernelGGL(k_pass2, dim3(NBLK), dim3(256), 0, stream, Qg, Kg, Vg, KLg, Sc, Ksc, Og);
}

// Round 8
// 51.992 us; speedup vs baseline: 1.8633x; 1.8633x over previous
//
#include <hip/hip_runtime.h>
#include <math.h>

#define NN 4
#define LL 4096
#define HH 8
#define EE 64
#define CHK 64            // compute chunk rows
#define GSUP 2            // chunks per super-chunk
#define SUPC (CHK*GSUP)   // 128 rows
#define NSUP (LL/SUPC)    // 32 supers per (n,h)
#define NH (NN*HH)        // 32
#define NBLK (NH*NSUP)    // 1024 blocks
#define NCH64 (LL/CHK)    // 64 chunks per (n,h)
#define EPSF 1e-6f

typedef float f32x4 __attribute__((ext_vector_type(4)));
typedef __bf16 bf16x8 __attribute__((ext_vector_type(8)));

__device__ __forceinline__ float phi_map(float x) {
  return x > 0.0f ? x + 1.0f : __expf(x);
}

#define MFMA(a, b, c) __builtin_amdgcn_mfma_f32_16x16x32_bf16((a), (b), (c), 0, 0, 0)

// ---- swizzled [64 rows][64 d] bf16 tile: 16B-block XOR along d (proven 0-conflict) ----
__device__ __forceinline__ int swz64(int row, int d) {
  return row * 64 + (d & 7) + 8 * ((d >> 3) ^ ((row >> 2) & 7));
}
__device__ __forceinline__ int frag64(int row, int blk) {
  return row * 64 + 8 * (blk ^ ((row >> 2) & 7));
}

// ================= Kernel 1: per-super-chunk S^T = sum_2tiles V^T K; per-64-chunk ksum =================
#define K1_ISSUE(J, BUF) { \
  const int l0i = (sc * GSUP + (J)) * CHK; \
  _Pragma("unroll") for (int it = 0; it < 4; ++it) { \
    int f = t + 256 * it; int d = f >> 4; int c4 = (f & 15) << 2; \
    size_t gb = (((size_t)n * LL + (size_t)(l0i + d)) * HH + h) * EE + c4; \
    pk[BUF][it] = *(const float4*)(Kg + gb); \
    pv[BUF][it] = *(const float4*)(Vg + gb); \
    pl[BUF][it] = KLg[n * LL + l0i + d]; } }

#define K1_STAGE(BUF) { \
  _Pragma("unroll") for (int it = 0; it < 4; ++it) { \
    int f = t + 256 * it; int d = f >> 4; int c4 = (f & 15) << 2; \
    float klr = pl[BUF][it]; float4 kk = pk[BUF][it]; float4 vv = pv[BUF][it]; \
    float ka[4] = {phi_map(kk.x) * klr, phi_map(kk.y) * klr, phi_map(kk.z) * klr, phi_map(kk.w) * klr}; \
    float va[4] = {vv.x, vv.y, vv.z, vv.w}; \
    _Pragma("unroll") for (int jj = 0; jj < 4; ++jj) { \
      sKt[BUF][swz64(c4 + jj, d)] = (__bf16)ka[jj]; \
      sVt[BUF][swz64(c4 + jj, d)] = (__bf16)va[jj]; } } }

__global__ __launch_bounds__(256, 2) void k_chunksums(
    const float* __restrict__ Kg, const float* __restrict__ Vg,
    const float* __restrict__ KLg, __bf16* __restrict__ ScG, __bf16* __restrict__ KscG)
{
  __shared__ __bf16 sKt[2][4096];
  __shared__ __bf16 sVt[2][4096];
  const int g = blockIdx.x;        // nh*NSUP + sc
  const int sc = g % NSUP;
  const int nh = g / NSUP;
  const int h = nh % HH;
  const int n = nh / HH;
  const int t = threadIdx.x;
  const int w = t >> 6;
  const int lane = t & 63;
  const int lg = lane >> 4;
  const int li = lane & 15;

  float4 pk[2][4], pv[2][4];
  float pl[2][4];

  K1_ISSUE(0, 0);
  K1_STAGE(0);

  f32x4 acc[4];
  #pragma unroll
  for (int nt = 0; nt < 4; ++nt) acc[nt] = (f32x4){0.f, 0.f, 0.f, 0.f};

  bf16x8 ones;
  #pragma unroll
  for (int i = 0; i < 8; ++i) ones[i] = (__bf16)1.0f;

  #pragma unroll
  for (int j = 0; j < GSUP; ++j) {
    if (j + 1 < GSUP) K1_ISSUE(j + 1, (j + 1) & 1);
    __syncthreads();

    bf16x8 aV0 = *(const bf16x8*)&sVt[j & 1][frag64(16 * w + li, lg)];
    bf16x8 aV1 = *(const bf16x8*)&sVt[j & 1][frag64(16 * w + li, 4 + lg)];

    f32x4 accK[4];
    #pragma unroll
    for (int nt = 0; nt < 4; ++nt) accK[nt] = (f32x4){0.f, 0.f, 0.f, 0.f};

    #pragma unroll
    for (int nt = 0; nt < 4; ++nt) {
      bf16x8 b0 = *(const bf16x8*)&sKt[j & 1][frag64(li + 16 * nt, lg)];
      bf16x8 b1 = *(const bf16x8*)&sKt[j & 1][frag64(li + 16 * nt, 4 + lg)];
      acc[nt] = MFMA(aV0, b0, acc[nt]);
      acc[nt] = MFMA(aV1, b1, acc[nt]);
      if (w == 0) {
        accK[nt] = MFMA(ones, b0, accK[nt]);
        accK[nt] = MFMA(ones, b1, accK[nt]);
      }
    }
    if (w == 0 && lg == 0) {
      #pragma unroll
      for (int nt = 0; nt < 4; ++nt)
        KscG[(size_t)(g * GSUP + j) * 64 + li + 16 * nt] = (__bf16)accK[nt][0];
    }
    if (j + 1 < GSUP) K1_STAGE((j + 1) & 1);
  }

  __bf16* sp = ScG + (size_t)g * 4096;
  #pragma unroll
  for (int nt = 0; nt < 4; ++nt)
    #pragma unroll
    for (int reg = 0; reg < 4; ++reg)
      sp[(16 * w + 4 * lg + reg) * 64 + li + 16 * nt] = (__bf16)acc[nt][reg];
}

// ================= Kernel 2: exclusive prefixes =================
__global__ __launch_bounds__(256) void k_prefix(
    __bf16* __restrict__ Sc, __bf16* __restrict__ Ksc)
{
  const int bid = blockIdx.x;
  const int t = threadIdx.x;
  if (bid < NH * 16) {
    const int nh = bid >> 4;
    const int strip = bid & 15;
    const int entry = strip * 256 + t;
    __bf16 v[NSUP];
    #pragma unroll
    for (int c = 0; c < NSUP; ++c)
      v[c] = Sc[((size_t)(nh * NSUP + c) << 12) + entry];
    float run = 0.0f;
    #pragma unroll
    for (int c = 0; c < NSUP; ++c) {
      Sc[((size_t)(nh * NSUP + c) << 12) + entry] = (__bf16)run;
      run += (float)v[c];
    }
  } else {
    const int idx = (bid - NH * 16) * 256 + t;
    const int nh = idx >> 6;
    const int e = idx & 63;
    __bf16 v[NCH64];
    #pragma unroll
    for (int c = 0; c < NCH64; ++c)
      v[c] = Ksc[((size_t)(nh * NCH64 + c) << 6) + e];
    float run = 0.0f;
    #pragma unroll
    for (int c = 0; c < NCH64; ++c) {
      Ksc[((size_t)(nh * NCH64 + c) << 6) + e] = (__bf16)run;
      run += (float)v[c];
    }
  }
}

// ================= Kernel 3: 4-wave per-super-chunk output, single-buffered LDS =================
#define P2_ISSUE(CC) { \
  const int l0i = (sc * GSUP + (CC)) * CHK; \
  _Pragma("unroll") for (int it = 0; it < 4; ++it) { \
    int f = t + 256 * it; int d = f >> 4; int c4 = (f & 15) << 2; \
    size_t gb = (((size_t)n * LL + (size_t)(l0i + d)) * HH + h) * EE + c4; \
    pk[it] = *(const float4*)(Kg + gb); \
    pv[it] = *(const float4*)(Vg + gb); \
    pl[it] = KLg[n * LL + l0i + d]; } \
  { const float* qr = Qg + (((size_t)n * LL + (size_t)(l0i + arow)) * HH + h) * EE; \
    pq[0] = *(const float4*)(qr + 8 * lg); \
    pq[1] = *(const float4*)(qr + 8 * lg + 4); \
    pq[2] = *(const float4*)(qr + 32 + 8 * lg); \
    pq[3] = *(const float4*)(qr + 32 + 8 * lg + 4); } }

#define P2_STAGE(QB) { \
  _Pragma("unroll") for (int it = 0; it < 4; ++it) { \
    int f = t + 256 * it; int d = f >> 4; int c4 = (f & 15) << 2; \
    float klr = pl[it]; float4 kk = pk[it]; float4 vv = pv[it]; \
    float ka[4] = {phi_map(kk.x) * klr, phi_map(kk.y) * klr, phi_map(kk.z) * klr, phi_map(kk.w) * klr}; \
    float va[4] = {vv.x, vv.y, vv.z, vv.w}; \
    _Pragma("unroll") for (int jj = 0; jj < 4; ++jj) { \
      sKe[swz64(d, c4 + jj)] = (__bf16)ka[jj]; \
      sKt[swz64(c4 + jj, d)] = (__bf16)ka[jj]; \
      sVt[swz64(c4 + jj, d)] = (__bf16)va[jj]; } } \
  { float4 q0 = pq[0], q1 = pq[1], q2 = pq[2], q3 = pq[3]; \
    bf16x8 a0, a1; \
    a0[0] = (__bf16)phi_map(q0.x); a0[1] = (__bf16)phi_map(q0.y); \
    a0[2] = (__bf16)phi_map(q0.z); a0[3] = (__bf16)phi_map(q0.w); \
    a0[4] = (__bf16)phi_map(q1.x); a0[5] = (__bf16)phi_map(q1.y); \
    a0[6] = (__bf16)phi_map(q1.z); a0[7] = (__bf16)phi_map(q1.w); \
    a1[0] = (__bf16)phi_map(q2.x); a1[1] = (__bf16)phi_map(q2.y); \
    a1[2] = (__bf16)phi_map(q2.z); a1[3] = (__bf16)phi_map(q2.w); \
    a1[4] = (__bf16)phi_map(q3.x); a1[5] = (__bf16)phi_map(q3.y); \
    a1[6] = (__bf16)phi_map(q3.z); a1[7] = (__bf16)phi_map(q3.w); \
    aQ[QB][0] = a0; aQ[QB][1] = a1; } }

__global__ __launch_bounds__(256, 2) void k_pass2(
    const float* __restrict__ Qg, const float* __restrict__ Kg,
    const float* __restrict__ Vg, const float* __restrict__ KLg,
    const __bf16* __restrict__ Sp, const __bf16* __restrict__ Ksp,
    float* __restrict__ Og)
{
  __shared__ __bf16 sKe[4096];    // phi(K)*kl [d][e] swizzled    (attn B)
  __shared__ __bf16 sKt[4096];    // K^T [e][d] swizzled          (state B)
  __shared__ __bf16 sVt[4096];    // V^T [m][d] swizzled          (PV B / state A)
  __shared__ __bf16 sU[4096];     // S^T [m][e] swizzled; P overlay between barriers B..A

  const int g = blockIdx.x;       // nh*NSUP + sc
  const int sc = g % NSUP;
  const int nh = g / NSUP;
  const int h = nh % HH;
  const int n = nh / HH;
  const int t = threadIdx.x;
  const int w = t >> 6;
  const int lane = t & 63;
  const int lg = lane >> 4;
  const int li = lane & 15;
  const int arow = 16 * w + li;

  float4 pk[4], pv[4], pq[4];
  float pl[4];
  bf16x8 aQ[2][2];

  // ---- stage S^T super-prefix into sU (swizzled) ----
  {
    const bf16x8* sp8 = (const bf16x8*)(Sp + (size_t)g * 4096);
    bf16x8 s0 = sp8[2 * t];
    bf16x8 s1 = sp8[2 * t + 1];
    int m = t >> 2, eb = (t & 3) * 2;
    *(bf16x8*)&sU[frag64(m, eb)] = s0;
    *(bf16x8*)&sU[frag64(m, eb + 1)] = s1;
  }

  P2_ISSUE(0);
  P2_STAGE(0);

  f32x4 accS[4];

  #pragma unroll
  for (int cc = 0; cc < GSUP; ++cc) {
    __syncthreads();   // A: STAGE(cc) + sU (initial or state writeback) visible

    if (cc == 0) {
      // seed state accumulator with the super-prefix (C-frag positions)
      #pragma unroll
      for (int nt = 0; nt < 4; ++nt)
        #pragma unroll
        for (int reg = 0; reg < 4; ++reg)
          accS[nt][reg] = (float)sU[swz64(16 * w + 4 * lg + reg, li + 16 * nt)];
    }

    if (cc + 1 < GSUP) P2_ISSUE(cc + 1);   // regs free (STAGE(cc) consumed them)

    bf16x8 aQ0 = aQ[cc & 1][0], aQ1 = aQ[cc & 1][1];

    // ---- inter: acc = Q * S ----
    f32x4 acc[4];
    #pragma unroll
    for (int nt = 0; nt < 4; ++nt) {
      acc[nt] = (f32x4){0.f, 0.f, 0.f, 0.f};
      bf16x8 b0 = *(const bf16x8*)&sU[frag64(li + 16 * nt, lg)];
      bf16x8 b1 = *(const bf16x8*)&sU[frag64(li + 16 * nt, 4 + lg)];
      acc[nt] = MFMA(aQ0, b0, acc[nt]);
      acc[nt] = MFMA(aQ1, b1, acc[nt]);
    }

    // ---- den = q . ksum_prefix ----
    const __bf16* kb = Ksp + (size_t)(g * GSUP + cc) * 64;
    bf16x8 ks0 = *(const bf16x8*)(kb + 8 * lg);
    bf16x8 ks1 = *(const bf16x8*)(kb + 32 + 8 * lg);
    float dv = 0.0f;
    #pragma unroll
    for (int i = 0; i < 8; ++i) {
      dv += (float)aQ0[i] * (float)ks0[i];
      dv += (float)aQ1[i] * (float)ks1[i];
    }
    dv += __shfl_xor(dv, 16);
    dv += __shfl_xor(dv, 32);
    float den[4];
    #pragma unroll
    for (int reg = 0; reg < 4; ++reg) den[reg] = __shfl(dv, 4 * lg + reg);

    __syncthreads();   // B: all sU inter-reads done -> P may overlay

    // ---- intra: masked attn -> P into sU (each wave overlays its own 16 rows) ----
    float rs[4] = {0.f, 0.f, 0.f, 0.f};
    #pragma unroll
    for (int nt = 0; nt < 4; ++nt) {
      f32x4 at2 = (f32x4){0.f, 0.f, 0.f, 0.f};
      if (nt <= w) {
        bf16x8 b0 = *(const bf16x8*)&sKe[frag64(li + 16 * nt, lg)];
        bf16x8 b1 = *(const bf16x8*)&sKe[frag64(li + 16 * nt, 4 + lg)];
        at2 = MFMA(aQ0, b0, at2);
        at2 = MFMA(aQ1, b1, at2);
      }
      #pragma unroll
      for (int reg = 0; reg < 4; ++reg) {
        int row = 16 * w + 4 * lg + reg;
        int col = li + 16 * nt;
        float av = (col <= row) ? at2[reg] : 0.0f;
        rs[reg] += av;
        sU[swz64(row, col)] = (__bf16)av;
      }
    }

    // ---- rowsum reduce (cols are fully wave-local) ----
    #pragma unroll
    for (int reg = 0; reg < 4; ++reg) {
      float v = rs[reg];
      v += __shfl_xor(v, 1);
      v += __shfl_xor(v, 2);
      v += __shfl_xor(v, 4);
      v += __shfl_xor(v, 8);
      rs[reg] = v;
    }

    // ---- PV: acc += P * V  (P rows are wave-private; no barrier needed) ----
    {
      bf16x8 aP0 = *(const bf16x8*)&sU[frag64(arow, lg)];
      bf16x8 aP1 = aP0;
      if (w >= 2) aP1 = *(const bf16x8*)&sU[frag64(arow, 4 + lg)];
      #pragma unroll
      for (int nt = 0; nt < 4; ++nt) {
        bf16x8 bv0 = *(const bf16x8*)&sVt[frag64(li + 16 * nt, lg)];
        acc[nt] = MFMA(aP0, bv0, acc[nt]);
        if (w >= 2) {
          bf16x8 bv1 = *(const bf16x8*)&sVt[frag64(li + 16 * nt, 4 + lg)];
          acc[nt] = MFMA(aP1, bv1, acc[nt]);
        }
      }
    }

    // ---- normalize + store ----
    const int l0 = (sc * GSUP + cc) * CHK;
    #pragma unroll
    for (int reg = 0; reg < 4; ++reg) {
      float inv = 1.0f / (den[reg] + rs[reg] + EPSF);
      int row = l0 + 16 * w + 4 * lg + reg;
      size_t ob = (((size_t)n * LL + row) * HH + h) * EE + li;
      #pragma unroll
      for (int nt = 0; nt < 4; ++nt)
        Og[ob + 16 * nt] = acc[nt][reg] * inv;
    }

    // ---- state update S^T += K^T V; write back into sU (own rows, clobbers P) ----
    if (cc + 1 < GSUP) {
      bf16x8 aV0 = *(const bf16x8*)&sVt[frag64(arow, lg)];
      bf16x8 aV1 = *(const bf16x8*)&sVt[frag64(arow, 4 + lg)];
      #pragma unroll
      for (int nt = 0; nt < 4; ++nt) {
        bf16x8 bk0 = *(const bf16x8*)&sKt[frag64(li + 16 * nt, lg)];
        bf16x8 bk1 = *(const bf16x8*)&sKt[frag64(li + 16 * nt, 4 + lg)];
        accS[nt] = MFMA(aV0, bk0, accS[nt]);
        accS[nt] = MFMA(aV1, bk1, accS[nt]);
        #pragma unroll
        for (int reg = 0; reg < 4; ++reg)
          sU[swz64(16 * w + 4 * lg + reg, li + 16 * nt)] = (__bf16)accS[nt][reg];
      }

      __syncthreads();   // C: all reads of sKe/sKt/sVt for chunk cc done -> restage
      P2_STAGE((cc + 1) & 1);
    }
  }
}

extern "C" void kernel_launch(void* const* d_in, const int* in_sizes, int n_in,
                              void* d_out, int out_size, void* d_ws, size_t ws_size,
                              hipStream_t stream) {
  const float* Qg  = (const float*)d_in[0];
  const float* Kg  = (const float*)d_in[1];
  const float* Vg  = (const float*)d_in[2];
  const float* KLg = (const float*)d_in[3];
  float* Og = (float*)d_out;

  // ws: Sc bf16 1024*4096*2 = 8MB | Ksc bf16 2048*64*2 = 256KB (prefix in place)
  __bf16* Sc  = (__bf16*)d_ws;
  __bf16* Ksc = (__bf16*)((char*)d_ws + (size_t)NBLK * 4096 * 2);

  hipLaunchKernelGGL(k_chunksums, dim3(NBLK), dim3(256), 0, stream, Kg, Vg, KLg, Sc, Ksc);
  hipLaunchKernelGGL(k_prefix, dim3(NH * 16 + 8), dim3(256), 0, stream, Sc, Ksc);
  hipLaunchKernelGGL(k_pass2, dim3(NBLK), dim3(256), 0, stream, Qg, Kg, Vg, KLg, Sc, Ksc, Og);
}